// Round 1
// baseline (457.395 us; speedup 1.0000x reference)
//
#include <hip/hip_runtime.h>
#include <hip/hip_bf16.h>
#include <stdint.h>

#define Bsz 4096
#define Csz 10000
#define Dsz 256
#define BM 128
#define BN 128
#define BK 32
#define KST 40   // LDS row stride in bf16 elems: 80 B, keeps ds_read_b128 16B-aligned, breaks bank pattern

typedef __attribute__((ext_vector_type(8))) __bf16 bf16x8;  // V8y — matches gfx950 mfma builtin signature
typedef __attribute__((ext_vector_type(4))) float f32x4;

__device__ __forceinline__ unsigned int f2bf(float x) {
    // round-to-nearest-even fp32 -> bf16 (inputs are finite normals; no NaN handling needed)
    unsigned int u = __float_as_uint(x);
    return (u + 0x7fffu + ((u >> 16) & 1u)) >> 16;
}
__device__ __forceinline__ unsigned int pack2(float a, float b) {
    return f2bf(a) | (f2bf(b) << 16);
}

// ---- kernel 1: f_sq[b], c_sq[c] into ws; zero the likelihood slot ----
__global__ __launch_bounds__(256) void sqnorm_kernel(
        const float* __restrict__ feat, const float* __restrict__ centers,
        float* __restrict__ ws, float* __restrict__ like_out) {
    if (blockIdx.x == 0 && threadIdx.x == 0) *like_out = 0.f;
    int row  = blockIdx.x * 4 + (threadIdx.x >> 6);
    int lane = threadIdx.x & 63;
    if (row >= Bsz + Csz) return;
    const float* src = (row < Bsz) ? feat + (size_t)row * Dsz
                                   : centers + (size_t)(row - Bsz) * Dsz;
    float4 v = *(const float4*)(src + lane * 4);
    float s = v.x * v.x + v.y * v.y + v.z * v.z + v.w * v.w;
    #pragma unroll
    for (int o = 32; o > 0; o >>= 1) s += __shfl_down(s, o);
    if (lane == 0) ws[row] = s;
}

// ---- kernel 2: likelihood = sum_b ||feat[b]-centers[label[b]]||^2 / (2B) ----
__global__ __launch_bounds__(256) void like_kernel(
        const float* __restrict__ feat, const float* __restrict__ centers,
        const int* __restrict__ label, float* __restrict__ like_out) {
    int row  = blockIdx.x * 4 + (threadIdx.x >> 6);
    int lane = threadIdx.x & 63;
    int lb = label[row];
    float4 f = *(const float4*)(feat + (size_t)row * Dsz + lane * 4);
    float4 c = *(const float4*)(centers + (size_t)lb * Dsz + lane * 4);
    float dx = f.x - c.x, dy = f.y - c.y, dz = f.z - c.z, dw = f.w - c.w;
    float s = dx * dx + dy * dy + dz * dz + dw * dw;
    #pragma unroll
    for (int o = 32; o > 0; o >>= 1) s += __shfl_down(s, o);
    if (lane == 0) atomicAdd(like_out, s * (1.0f / (2.0f * Bsz)));
}

// ---- kernel 3: fused GEMM + dist + logits/margin epilogue ----
// 128x128 tile, 4 waves (2x2), each wave 4x4 of mfma_f32_16x16x32_bf16.
// cross[b,c] = feat[b,:] . centers[c,:]  (both K-contiguous -> symmetric A/B staging)
// logits = cross - 0.5*(f_sq + c_sq); margin = logits * (c==label[b] ? 1.1 : 1.0)
__global__ __launch_bounds__(256) void lgm_gemm_kernel(
        const float* __restrict__ feat, const float* __restrict__ centers,
        const int* __restrict__ label, const float* __restrict__ fsq,
        const float* __restrict__ csq, float* __restrict__ out) {
    __shared__ unsigned short As[BM * KST];
    __shared__ unsigned short Bs[BN * KST];
    __shared__ float Fs[BM];
    __shared__ float Cq[BN];
    __shared__ int   Lb[BM];

    const int tid     = threadIdx.x;
    const int rowBase = blockIdx.y * BM;   // B rows: 4096 % 128 == 0, no row guard
    const int colBase = blockIdx.x * BN;   // C cols: 10000 % 128 == 16, guard last tile

    if (tid < 128) {
        Fs[tid] = fsq[rowBase + tid];
        Lb[tid] = label[rowBase + tid];
        int c = colBase + tid;
        Cq[tid] = (c < Csz) ? csq[c] : 0.f;
    }

    const int lane = tid & 63;
    const int wv   = tid >> 6;
    const int wr   = (wv >> 1) * 64;   // wave row offset in tile
    const int wc   = (wv & 1) * 64;    // wave col offset in tile
    const int quad = lane >> 4;
    const int l15  = lane & 15;

    f32x4 acc[4][4];
    #pragma unroll
    for (int i = 0; i < 4; ++i)
        #pragma unroll
        for (int j = 0; j < 4; ++j)
            acc[i][j] = (f32x4){0.f, 0.f, 0.f, 0.f};

    const int sr = tid >> 3;  // staging row 0..31
    const int sf = tid & 7;   // staging float4 index within 32-wide K slab

    for (int k0 = 0; k0 < Dsz; k0 += BK) {
        __syncthreads();  // previous iter's LDS reads done before overwrite
        #pragma unroll
        for (int rr = 0; rr < BM; rr += 32) {
            int r = sr + rr;
            float4 v = *(const float4*)(feat + (size_t)(rowBase + r) * Dsz + k0 + sf * 4);
            *(uint2*)(As + r * KST + sf * 4) = make_uint2(pack2(v.x, v.y), pack2(v.z, v.w));
        }
        #pragma unroll
        for (int rr = 0; rr < BN; rr += 32) {
            int r = sr + rr;
            int crow = colBase + r;
            if (crow >= Csz) crow = Csz - 1;  // clamp: stores are masked later
            float4 v = *(const float4*)(centers + (size_t)crow * Dsz + k0 + sf * 4);
            *(uint2*)(Bs + r * KST + sf * 4) = make_uint2(pack2(v.x, v.y), pack2(v.z, v.w));
        }
        __syncthreads();

        bf16x8 af[4], bfr[4];
        #pragma unroll
        for (int mi = 0; mi < 4; ++mi)
            af[mi] = *(const bf16x8*)(As + (wr + mi * 16 + l15) * KST + quad * 8);
        #pragma unroll
        for (int ni = 0; ni < 4; ++ni)
            bfr[ni] = *(const bf16x8*)(Bs + (wc + ni * 16 + l15) * KST + quad * 8);
        #pragma unroll
        for (int mi = 0; mi < 4; ++mi)
            #pragma unroll
            for (int ni = 0; ni < 4; ++ni)
                acc[mi][ni] = __builtin_amdgcn_mfma_f32_16x16x32_bf16(
                    af[mi], bfr[ni], acc[mi][ni], 0, 0, 0);
    }

    // epilogue: C/D layout col=lane&15, row=quad*4+reg (verified m89/m91)
    float* outL = out;
    float* outM = out + (size_t)Bsz * Csz;
    #pragma unroll
    for (int mi = 0; mi < 4; ++mi) {
        const int rT0 = wr + mi * 16 + quad * 4;
        float fr[4]; int lb[4]; int gr[4];
        #pragma unroll
        for (int r = 0; r < 4; ++r) {
            fr[r] = Fs[rT0 + r];
            lb[r] = Lb[rT0 + r];
            gr[r] = rowBase + rT0 + r;
        }
        #pragma unroll
        for (int ni = 0; ni < 4; ++ni) {
            const int cT = wc + ni * 16 + l15;
            const int gc = colBase + cT;
            if (gc >= Csz) continue;
            const float cs = Cq[cT];
            f32x4 a = acc[mi][ni];
            #pragma unroll
            for (int r = 0; r < 4; ++r) {
                float logit = a[r] - 0.5f * (fr[r] + cs);
                float marg  = (gc == lb[r]) ? logit * 1.1f : logit;
                size_t off = (size_t)gr[r] * Csz + gc;
                outL[off] = logit;
                outM[off] = marg;
            }
        }
    }
}

extern "C" void kernel_launch(void* const* d_in, const int* in_sizes, int n_in,
                              void* d_out, int out_size, void* d_ws, size_t ws_size,
                              hipStream_t stream) {
    const float* feat    = (const float*)d_in[0];
    const int*   label   = (const int*)d_in[1];
    const float* centers = (const float*)d_in[2];
    float* out = (float*)d_out;
    float* fsq = (float*)d_ws;          // [4096]
    float* csq = fsq + Bsz;             // [10000]
    float* like_out = out + (size_t)2 * Bsz * Csz;

    sqnorm_kernel<<<dim3((Bsz + Csz + 3) / 4), 256, 0, stream>>>(feat, centers, fsq, like_out);
    like_kernel<<<dim3(Bsz / 4), 256, 0, stream>>>(feat, centers, label, like_out);
    lgm_gemm_kernel<<<dim3((Csz + BN - 1) / BN, Bsz / BM), 256, 0, stream>>>(
        feat, centers, label, fsq, csq, out);
}